// Round 1
// baseline (2467.887 us; speedup 1.0000x reference)
//
#include <hip/hip_runtime.h>
#include <cstdint>
#include <cstddef>

// ---------------------------------------------------------------------------
// Residual VQ (SoundStream Alg.1) on MI355X.
// Strategy: per-WG point-parallel chain (32 pts/WG, 8 quantizers sequential in
// LDS). fp32 distance GEMM (tile 8pts x 16codes/thread, dbuf LDS staging of
// k-major transposed codebook via global_load_lds), exact fp64 refinement of
// argmin near-ties (margin eps) so emitted indices equal exact-arithmetic
// argmin. Commit losses accumulated in fp64 via global atomics.
// ---------------------------------------------------------------------------

#define BATCH 8
#define SEQ   2048
#define DIM   512
#define NUMQ  8
#define CODES 1024
#define NPTS  (BATCH*SEQ)            // 16384
#define MPTS  32                     // points per workgroup
#define NWG   (NPTS/MPTS)            // 512
#define NTHR  256
#define KC    8                      // k-chunk depth staged per buffer
#define NKC   (DIM/KC)               // 64

#define OUT_IDX   (BATCH*SEQ*DIM)             // 8388608
#define OUT_LOSS  (OUT_IDX + BATCH*SEQ*NUMQ)  // 8519680

#define WS_LOSS    0                          // 8 doubles
#define WS_CNORM   1024                       // 8192 floats
#define WS_CBT     40960                      // 8*512*1024 floats (k-major)
#define WS_NEED_T  (WS_CBT + (size_t)NUMQ*DIM*CODES*4)

__global__ void k_zero(double* loss) {
  if (threadIdx.x < NUMQ) loss[threadIdx.x] = 0.0;
}

// per-code squared norm (fp32; only feeds the approximate fp32 scores)
__global__ void k_cnorm(const float* __restrict__ cb, float* __restrict__ cnorm) {
  int r = blockIdx.x * blockDim.x + threadIdx.x;      // 0..8191
  const float* row = cb + (size_t)r * DIM;
  float s = 0.f;
  for (int d = 0; d < DIM; ++d) s += row[d] * row[d];
  cnorm[r] = s;
}

// cbT[q][k][c] = cb[q][c][k]  (coalesced writes; reads absorbed by L2/L3)
__global__ void k_transpose(const float* __restrict__ cb, float* __restrict__ cbT) {
  unsigned t = blockIdx.x * blockDim.x + threadIdx.x;  // 0..4194303
  unsigned c = t & (CODES - 1);
  unsigned k = (t >> 10) & (DIM - 1);
  unsigned q = t >> 19;
  cbT[t] = cb[(((size_t)q << 10) | c) * DIM + k];
}

__device__ __forceinline__ float getc(const float4& v, int k) {
  return k == 0 ? v.x : k == 1 ? v.y : k == 2 ? v.z : v.w;
}

// Stage one k-chunk (KC x 1024 floats = 32KB) into LDS, layout [k][c].
// useT: coalesced global_load_lds from transposed codebook (dest = uniform
// wave base + lane*16, matching lane-consecutive float4 slots).
// else: gather dwordx4 from original layout + LDS scatter (slow fallback).
__device__ __forceinline__ void stage_chunk(const float* __restrict__ src, float* st,
                                            int q, int kc, int tid, int pg, int useT)
{
  if (useT) {
    const float* g = src + ((size_t)q * DIM + (size_t)kc * KC) * CODES + (tid << 2);
    float* l = st + (pg << 8);   // wave-uniform base (floats); HW adds lane*16B
    #pragma unroll
    for (int i = 0; i < KC; ++i) {
      __builtin_amdgcn_global_load_lds(
          (const __attribute__((address_space(1))) void*)(g + i * CODES),
          (__attribute__((address_space(3))) void*)(l + i * CODES), 16, 0, 0);
    }
  } else {
    #pragma unroll
    for (int i = 0; i < 8; ++i) {
      const int id = (i << 8) + tid;          // 0..2047
      const int c = id >> 1, h = id & 1;
      const float4 v = *(const float4*)(src + ((size_t)q * CODES + c) * DIM + kc * KC + (h << 2));
      st[((h << 2) + 0) * CODES + c] = v.x;
      st[((h << 2) + 1) * CODES + c] = v.y;
      st[((h << 2) + 2) * CODES + c] = v.z;
      st[((h << 2) + 3) * CODES + c] = v.w;
    }
  }
}

__launch_bounds__(NTHR, 1)
__global__ void k_main(const float* __restrict__ x, const float* __restrict__ cb,
                       const float* __restrict__ cbSrc,   // cbT if useT else cb
                       const float* __restrict__ cnorm,
                       double* __restrict__ lossAcc,
                       float* __restrict__ out, int useT)
{
  __shared__ __align__(16) float resid[MPTS][DIM];      // 64 KB fp32 residual
  __shared__ __align__(16) float stage[2][KC][CODES];   // 64 KB double-buffered codes
  __shared__ int idxs[MPTS][NUMQ];                      // chosen code per (pt,q)
  __shared__ double lred[4];

  const int tid = threadIdx.x;
  const int wg  = blockIdx.x;
  const int cl  = tid & 63;        // lane in wave
  const int pg  = tid >> 6;        // wave id == point-group (8 pts each)

  // ---- init residual = x (canonical coalesced/conflict-free float4 pattern)
  for (int t = tid; t < MPTS * DIM / 4; t += NTHR) {
    int p = t >> 7, d4 = t & 127;
    float4 v = *(const float4*)(x + ((size_t)(wg * MPTS + p)) * DIM + d4 * 4);
    *(float4*)&resid[p][d4 * 4] = v;
  }
  __syncthreads();

  for (int q = 0; q < NUMQ; ++q) {
    // acc[ii][g] covers codes c = g*256 + cl*4 + comp for point pg*8+ii
    float4 acc[8][4];
    #pragma unroll
    for (int ii = 0; ii < 8; ++ii)
      #pragma unroll
      for (int g = 0; g < 4; ++g) acc[ii][g] = make_float4(0.f, 0.f, 0.f, 0.f);

    stage_chunk(cbSrc, &stage[0][0][0], q, 0, tid, pg, useT);
    __syncthreads();

    #pragma unroll 1
    for (int kc = 0; kc < NKC; ++kc) {
      if (kc + 1 < NKC)
        stage_chunk(cbSrc, &stage[(kc + 1) & 1][0][0], q, kc + 1, tid, pg, useT);
      const float* st = &stage[kc & 1][0][0];
      const int rb = kc * KC;
      #pragma unroll
      for (int k4 = 0; k4 < 2; ++k4) {
        float4 rv[8];
        #pragma unroll
        for (int ii = 0; ii < 8; ++ii)
          rv[ii] = *(const float4*)&resid[(pg << 3) + ii][rb + (k4 << 2)];  // broadcast
        #pragma unroll
        for (int kk = 0; kk < 4; ++kk) {
          float4 cv[4];
          #pragma unroll
          for (int g = 0; g < 4; ++g)
            cv[g] = *(const float4*)&st[((k4 << 2) + kk) * CODES + (g << 8) + (cl << 2)];
          #pragma unroll
          for (int ii = 0; ii < 8; ++ii) {
            const float r = getc(rv[ii], kk);
            #pragma unroll
            for (int g = 0; g < 4; ++g) {
              acc[ii][g].x = fmaf(r, cv[g].x, acc[ii][g].x);
              acc[ii][g].y = fmaf(r, cv[g].y, acc[ii][g].y);
              acc[ii][g].z = fmaf(r, cv[g].z, acc[ii][g].z);
              acc[ii][g].w = fmaf(r, cv[g].w, acc[ii][g].w);
            }
          }
        }
      }
      __syncthreads();
    }

    // ---- scores = -2*dot + ||c||^2 (fp32, approximate; eps covers error)
    {
      const float* cnq = cnorm + q * CODES;
      float4 cn[4];
      #pragma unroll
      for (int g = 0; g < 4; ++g) cn[g] = *(const float4*)&cnq[(g << 8) + (cl << 2)];
      #pragma unroll
      for (int ii = 0; ii < 8; ++ii)
        #pragma unroll
        for (int g = 0; g < 4; ++g) {
          acc[ii][g].x = -2.0f * acc[ii][g].x + cn[g].x;
          acc[ii][g].y = -2.0f * acc[ii][g].y + cn[g].y;
          acc[ii][g].z = -2.0f * acc[ii][g].z + cn[g].z;
          acc[ii][g].w = -2.0f * acc[ii][g].w + cn[g].w;
        }
    }

    // ---- per-point argmin with exact fp64 near-tie refinement (per wave)
    #pragma unroll
    for (int i = 0; i < 8; ++i) {
      const int cbase = (cl << 2);
      float s1 = acc[i][0].x; int i1 = cbase;
      {
        auto upd = [&](float s, int id) { if (s < s1) { s1 = s; i1 = id; } };
        upd(acc[i][0].y, cbase + 1); upd(acc[i][0].z, cbase + 2); upd(acc[i][0].w, cbase + 3);
        #pragma unroll
        for (int g = 1; g < 4; ++g) {
          int b = (g << 8) + cbase;
          upd(acc[i][g].x, b); upd(acc[i][g].y, b + 1);
          upd(acc[i][g].z, b + 2); upd(acc[i][g].w, b + 3);
        }
      }
      #pragma unroll
      for (int m = 1; m < 64; m <<= 1) {
        float os = __shfl_xor(s1, m); int oid = __shfl_xor(i1, m);
        if (os < s1 || (os == s1 && oid < i1)) { s1 = os; i1 = oid; }
      }

      const float lim = s1 + 0.25f + 5e-5f * fabsf(s1);
      int c0 = i1, c1 = -1, c2 = -1, c3 = -1, c4 = -1; int nc = 1;
      #pragma unroll 1
      for (int r = 0; r < 4; ++r) {
        float sb = 3.0e38f; int ib = 0x7FFFFFFF;
        auto cons = [&](float s, int id) {
          if (s <= lim && id != c0 && id != c1 && id != c2 && id != c3 && id != c4) {
            if (s < sb || (s == sb && id < ib)) { sb = s; ib = id; }
          }
        };
        #pragma unroll
        for (int g = 0; g < 4; ++g) {
          int b = (g << 8) + cbase;
          cons(acc[i][g].x, b); cons(acc[i][g].y, b + 1);
          cons(acc[i][g].z, b + 2); cons(acc[i][g].w, b + 3);
        }
        #pragma unroll
        for (int m = 1; m < 64; m <<= 1) {
          float os = __shfl_xor(sb, m); int oid = __shfl_xor(ib, m);
          if (os < sb || (os == sb && oid < ib)) { sb = os; ib = oid; }
        }
        if (ib == 0x7FFFFFFF) break;
        if (r == 0) c1 = ib; else if (r == 1) c2 = ib; else if (r == 2) c3 = ib; else c4 = ib;
        ++nc;
      }

      int winner = i1;
      if (nc > 1) {
        // exact fp64: rebuild residual chain ((x-c0)-c1)-... (bit-exact fp64 op order)
        const int p = (pg << 3) + i;
        const size_t gp = (size_t)wg * MPTS + p;
        double rh[8];
        const float* xr = x + gp * DIM + (cl << 3);
        #pragma unroll
        for (int j = 0; j < 8; ++j) rh[j] = (double)xr[j];
        #pragma unroll 1
        for (int t = 0; t < q; ++t) {
          const float* cr = cb + ((size_t)t * CODES + idxs[p][t]) * DIM + (cl << 3);
          #pragma unroll
          for (int j = 0; j < 8; ++j) rh[j] -= (double)cr[j];
        }
        double bs = 1.0e300; int bi = 0x7FFFFFFF;
        #pragma unroll 1
        for (int t = 0; t < 5; ++t) {
          if (t >= nc) break;
          const int cc = (t == 0) ? c0 : (t == 1) ? c1 : (t == 2) ? c2 : (t == 3) ? c3 : c4;
          const float* cr = cb + ((size_t)q * CODES + cc) * DIM + (cl << 3);
          double dt = 0.0, cs = 0.0;
          #pragma unroll
          for (int j = 0; j < 8; ++j) {
            double cd = (double)cr[j];
            dt += rh[j] * cd; cs += cd * cd;
          }
          #pragma unroll
          for (int m = 1; m < 64; m <<= 1) { dt += __shfl_xor(dt, m); cs += __shfl_xor(cs, m); }
          double s = -2.0 * dt + cs;
          if (s < bs || (s == bs && cc < bi)) { bs = s; bi = cc; }
        }
        winner = bi;
      }
      if (cl == 0) idxs[(pg << 3) + i][q] = winner;
    }
    __syncthreads();

    // ---- residual update + commit-loss partial (bank-conflict-free swizzle:
    //      col4 = t*8 + (tid&7) => quad id == lane%8, canonical pattern)
    {
      const int p = tid >> 3;
      const int lane8 = tid & 7;
      const int w = idxs[p][q];
      const float4* cr = (const float4*)(cb + ((size_t)q * CODES + w) * DIM);
      float4* rr = (float4*)&resid[p][0];
      double ls = 0.0;
      #pragma unroll
      for (int t = 0; t < 16; ++t) {
        const int col4 = t * 8 + lane8;
        float4 qv = cr[col4], rv = rr[col4];
        float dx = qv.x - rv.x, dy = qv.y - rv.y, dz = qv.z - rv.z, dw = qv.w - rv.w;
        ls += (double)dx * dx + (double)dy * dy + (double)dz * dz + (double)dw * dw;
        rv.x -= qv.x; rv.y -= qv.y; rv.z -= qv.z; rv.w -= qv.w;
        rr[col4] = rv;
      }
      #pragma unroll
      for (int m = 1; m < 64; m <<= 1) ls += __shfl_xor(ls, m);
      if (cl == 0) lred[pg] = ls;
      __syncthreads();
      if (tid == 0) atomicAdd(lossAcc + q, lred[0] + lred[1] + lred[2] + lred[3]);
      __syncthreads();
    }
  } // q

  // ---- outputs: quantized = x - residual_final; indices as float
  for (int t = tid; t < MPTS * DIM / 4; t += NTHR) {
    int p = t >> 7, d4 = t & 127;
    size_t off = ((size_t)(wg * MPTS + p)) * DIM + d4 * 4;
    float4 xv = *(const float4*)(x + off);
    float4 rv = *(const float4*)&resid[p][d4 * 4];
    float4 o;
    o.x = xv.x - rv.x; o.y = xv.y - rv.y; o.z = xv.z - rv.z; o.w = xv.w - rv.w;
    *(float4*)(out + off) = o;
  }
  if (tid < MPTS) {
    const size_t gp = (size_t)wg * MPTS + tid;
    float* ob = out + OUT_IDX + gp * NUMQ;
    #pragma unroll
    for (int j = 0; j < NUMQ; ++j) ob[j] = (float)idxs[tid][j];
  }
}

__global__ void k_fin(const double* __restrict__ loss, float* __restrict__ out) {
  int t = threadIdx.x;
  if (t < NUMQ)
    out[OUT_LOSS + t] = (float)(loss[t] / (double)((size_t)BATCH * SEQ * DIM));
}

extern "C" void kernel_launch(void* const* d_in, const int* in_sizes, int n_in,
                              void* d_out, int out_size, void* d_ws, size_t ws_size,
                              hipStream_t stream) {
  (void)in_sizes; (void)n_in; (void)out_size;
  const float* x  = (const float*)d_in[0];
  const float* cb = (const float*)d_in[1];
  float* out = (float*)d_out;
  char* ws = (char*)d_ws;
  double* loss = (double*)(ws + WS_LOSS);
  float* cnorm = (float*)(ws + WS_CNORM);
  float* cbT   = (float*)(ws + WS_CBT);
  const int useT = (ws_size >= WS_NEED_T) ? 1 : 0;

  k_zero<<<1, 64, 0, stream>>>(loss);
  k_cnorm<<<NUMQ * CODES / NTHR, NTHR, 0, stream>>>(cb, cnorm);
  if (useT)
    k_transpose<<<NUMQ * CODES * DIM / NTHR, NTHR, 0, stream>>>(cb, cbT);
  k_main<<<NWG, NTHR, 0, stream>>>(x, cb, useT ? cbT : cb, cnorm, loss, out, useT);
  k_fin<<<1, 64, 0, stream>>>(loss, out);
}